// Round 18
// baseline (278.139 us; speedup 1.0000x reference)
//
#include <hip/hip_runtime.h>

constexpr int NE = 8192;
constexpr int ED = 256;
constexpr int BS = 32768;
constexpr float DELTA = 4e-4f;   // >> bf16-MFMA err + key quant (7.6e-6) + e2-fusion (~3e-9)

typedef short bf16x8 __attribute__((ext_vector_type(8)));
typedef float f32x4 __attribute__((ext_vector_type(4)));

constexpr size_t WSTR = (size_t)NE * 64;   // ebT k-window stride (512 KB)

#define GLOAD_LDS16(g, l) __builtin_amdgcn_global_load_lds( \
    (const __attribute__((address_space(1))) void*)(g),     \
    (__attribute__((address_space(3))) void*)(l), 16, 0, 0)

__device__ __forceinline__ short f2bf(float f) {            // RNE f32 -> bf16
    unsigned u = __float_as_uint(f);
    u = u + 0x7FFFu + ((u >> 16) & 1u);
    return (short)(u >> 16);
}
__device__ __forceinline__ unsigned bf16_rd(float x) {      // round toward -inf -> bf16 bits
    unsigned u = __float_as_uint(x);
    unsigned h = u >> 16;
    if ((u & 0x80000000u) && (u & 0xFFFFu)) ++h;
    return h;
}
__device__ __forceinline__ unsigned umn(unsigned a, unsigned b) { return a < b ? a : b; }
__device__ __forceinline__ unsigned umx(unsigned a, unsigned b) { return a > b ? a : b; }
__device__ __forceinline__ unsigned med3(unsigned a, unsigned b, unsigned c) {
    unsigned r;
    asm("v_med3_u32 %0, %1, %2, %3" : "=v"(r) : "v"(a), "v"(b), "v"(c));
    return r;
}
__device__ __forceinline__ unsigned and_or(unsigned a, unsigned b, unsigned c) {
    unsigned r;
    asm("v_and_or_b32 %0, %1, %2, %3" : "=v"(r) : "v"(a), "v"(b), "v"(c));
    return r;
}

// ---------- np-exact pairwise ||row||^2 (verified bit-exact vs np.sum in R2) ----------
__global__ void sq_np_kernel(const float* __restrict__ a, float* __restrict__ out) {
    int gtid = blockIdx.x * blockDim.x + threadIdx.x;
    int wave = gtid >> 6;
    int lane = threadIdx.x & 63;
    int sub  = lane & 7;
    int row  = wave * 8 + (lane >> 3);
    const float* p = a + (size_t)row * ED;
    float b0 = 0.f, b1 = 0.f;
#pragma unroll
    for (int t = 0; t < 16; ++t) { float v = p[8 * t + sub];       b0 = __fadd_rn(b0, __fmul_rn(v, v)); }
#pragma unroll
    for (int t = 0; t < 16; ++t) { float v = p[128 + 8 * t + sub]; b1 = __fadd_rn(b1, __fmul_rn(v, v)); }
    b0 = __fadd_rn(b0, __shfl_xor(b0, 1));
    b0 = __fadd_rn(b0, __shfl_xor(b0, 2));
    b0 = __fadd_rn(b0, __shfl_xor(b0, 4));
    b1 = __fadd_rn(b1, __shfl_xor(b1, 1));
    b1 = __fadd_rn(b1, __shfl_xor(b1, 2));
    b1 = __fadd_rn(b1, __shfl_xor(b1, 4));
    if (sub == 0) out[row] = __fadd_rn(b0, b1);
}

// ---------- e -> ebT (bf16 of -2e, k-major) + fused e2 slot ----------
// layout [w][col][64B]; w=8 slot per col: {e2, 0.25, 0...} (zE {1,2} -> +e2+0.5)
__global__ void cvt_ebT_kernel(const float* __restrict__ e, const float* __restrict__ e2,
                               char* __restrict__ ebT) {
    int i = blockIdx.x * blockDim.x + threadIdx.x;     // one per 16B unit (262144)
    int c = i >> 5;                                    // e-row (col in GEMM)
    int u = i & 31;
    int w = u >> 2, lg = u & 3;
    const float* p = e + (size_t)c * ED + w * 32 + lg * 8;
    float4 v0 = *reinterpret_cast<const float4*>(p);
    float4 v1 = *reinterpret_cast<const float4*>(p + 4);
    bf16x8 h;
    h[0] = f2bf(v0.x * -2.f); h[1] = f2bf(v0.y * -2.f);
    h[2] = f2bf(v0.z * -2.f); h[3] = f2bf(v0.w * -2.f);
    h[4] = f2bf(v1.x * -2.f); h[5] = f2bf(v1.y * -2.f);
    h[6] = f2bf(v1.z * -2.f); h[7] = f2bf(v1.w * -2.f);
    *reinterpret_cast<bf16x8*>(ebT + (size_t)w * WSTR + (size_t)c * 64 + lg * 16) = h;
    if (i < NE) {                                      // e2 slot for col i
        bf16x8 s0 = {};
        s0[0] = f2bf(e2[i]);
        s0[1] = f2bf(0.25f);
        bf16x8 zz = {};
        char* qp = ebT + 8 * WSTR + (size_t)i * 64;
        *reinterpret_cast<bf16x8*>(qp)      = s0;
        *reinterpret_cast<bf16x8*>(qp + 16) = zz;
        *reinterpret_cast<bf16x8*>(qp + 32) = zz;
        *reinterpret_cast<bf16x8*>(qp + 48) = zz;
    }
}

// ---------- pass 1: 32-col LDS tiles (32KB -> 3+ blocks/CU), j=4, fused key ----------
// 4 waves x 64 rows = 256 rows/block; col-eighth (1024) = 32 tiles of 32.
// Numerics byte-identical to R15 (proven); med3 top-2 accumulated per 128-chunk.
__global__ __launch_bounds__(256, 2) void vq_pass1(
        const float* __restrict__ z, const char* __restrict__ ebT,
        uint2* __restrict__ wsp) {
    __shared__ __align__(16) char Bs[2][16384];      // 32-col tile double buffer

    const int tid  = threadIdx.x;
    const int wid  = tid >> 6, lane = tid & 63;
    const int l15  = lane & 15, lg = lane >> 4;
    const int kblk = blockIdx.x;
    const int rg   = (kblk & 7) | ((kblk >> 6) << 3);   // all eighths of a rg on one XCD
    const int q8   = (kblk >> 3) & 7;
    const int c0q  = q8 * 1024;
    const int wr0  = rg * 256 + wid * 64;

    // ---- staging source (pre-swizzled): LDS slot L holds logical (c=L>>5, r=(L&31)^(c&7))
    const char* gsrc[4];
#pragma unroll
    for (int it = 0; it < 4; ++it) {
        int L = it * 256 + tid;              // 0..1023
        int c = L >> 5;                      // col 0..31
        int r = (L & 31) ^ (c & 7);          // logical w*4+lg
        gsrc[it] = ebT + (size_t)(r >> 2) * WSTR + (size_t)(c0q + c) * 64 + (r & 3) * 16;
    }
#pragma unroll
    for (int it = 0; it < 4; ++it)           // stage tile 0
        GLOAD_LDS16(gsrc[it], &Bs[0][(it * 256 + tid) * 16]);

    // ---- z rows -> registers (bf16), 64 rows/wave, full K (hides tile-0 latency) ----
    bf16x8 zreg[4][8];
#pragma unroll
    for (int j = 0; j < 4; ++j) {
        const float* zr = z + (size_t)(wr0 + j * 16 + l15) * ED + lg * 8;
#pragma unroll
        for (int t8 = 0; t8 < 8; ++t8) {
            float4 v0 = *reinterpret_cast<const float4*>(zr + t8 * 32);
            float4 v1 = *reinterpret_cast<const float4*>(zr + t8 * 32 + 4);
            bf16x8 h;
            h[0] = f2bf(v0.x); h[1] = f2bf(v0.y); h[2] = f2bf(v0.z); h[3] = f2bf(v0.w);
            h[4] = f2bf(v1.x); h[5] = f2bf(v1.y); h[6] = f2bf(v1.z); h[7] = f2bf(v1.w);
            zreg[j][t8] = h;
        }
    }
    bf16x8 zE = {};                      // {1.0, 2.0} against {e2, 0.25} -> +e2+0.5
    if (lg == 0) { zE[0] = (short)0x3F80; zE[1] = (short)0x4000; }

    // ---- ds_read address components ----
    const int hsh = (l15 & 7) << 4;
    int xw[8];
#pragma unroll
    for (int w = 0; w < 8; ++w) xw[w] = (w * 64 + lg * 16) ^ hsh;
    const char* ebase = ebT + (size_t)(c0q + l15) * 64 + lg * 16;   // e2 slot reads

    bf16x8 bufE[2];
    unsigned rk1[4], rk2[4];
#pragma unroll
    for (int j = 0; j < 4; ++j) { rk1[j] = 0xFFFFFFFFu; rk2[j] = 0xFFFFFFFFu; }

    for (int t = 0; t < 32; ++t) {
        __syncthreads();                 // vmcnt-drain: tile t staged; prev reads done
        if (t < 31) {                    // issue next tile into other buffer (hidden)
#pragma unroll
            for (int it = 0; it < 4; ++it)
                GLOAD_LDS16(gsrc[it] + (size_t)(t + 1) * 2048,
                            &Bs[(t + 1) & 1][(it * 256 + tid) * 16]);
        }
        const char* B = Bs[t & 1];
        f32x4 acc[2][4];
#pragma unroll
        for (int s = 0; s < 4; ++s) {
            if (s == 0) {
#pragma unroll
                for (int i2 = 0; i2 < 2; ++i2)
#pragma unroll
                    for (int j = 0; j < 4; ++j) acc[i2][j] = (f32x4){0.f, 0.f, 0.f, 0.f};
                size_t colbyte = (size_t)t << 11;                 // t*32 cols * 64B
                bufE[0] = *reinterpret_cast<const bf16x8*>(ebase + 8 * WSTR + colbyte);
                bufE[1] = *reinterpret_cast<const bf16x8*>(ebase + 8 * WSTR + colbyte + 1024);
            }
            bf16x8 af[2][2];
#pragma unroll
            for (int i2 = 0; i2 < 2; ++i2)
#pragma unroll
                for (int tt = 0; tt < 2; ++tt)
                    af[i2][tt] = *reinterpret_cast<const bf16x8*>(
                        B + (size_t)(i2 * 16 + l15) * 512 + xw[s * 2 + tt]);

            __builtin_amdgcn_s_setprio(1);
#pragma unroll
            for (int tt = 0; tt < 2; ++tt)
#pragma unroll
                for (int i2 = 0; i2 < 2; ++i2)
#pragma unroll
                    for (int j = 0; j < 4; ++j)
                        acc[i2][j] = __builtin_amdgcn_mfma_f32_16x16x32_bf16(
                            af[i2][tt], zreg[j][s * 2 + tt],
                            acc[i2][j], 0, 0, 0);
            __builtin_amdgcn_s_setprio(0);

            if (s == 3) {                // tile epilogue
                __builtin_amdgcn_s_setprio(1);
#pragma unroll
                for (int i2 = 0; i2 < 2; ++i2)      // fused e2+0.5 term (w=8)
#pragma unroll
                    for (int j = 0; j < 4; ++j)
                        acc[i2][j] = __builtin_amdgcn_mfma_f32_16x16x32_bf16(
                            bufE[i2], zE, acc[i2][j], 0, 0, 0);
                __builtin_amdgcn_s_setprio(0);

                const unsigned cb = (unsigned)((t & 3) * 32 + lg * 4);
#pragma unroll
                for (int j = 0; j < 4; ++j) {
#pragma unroll
                    for (int i2 = 0; i2 < 2; ++i2) {
#pragma unroll
                        for (int qq = 0; qq < 4; ++qq) {
                            // acc IS d'+0.5 (positive): monotone u32 key
                            unsigned k = and_or(__float_as_uint(acc[i2][j][qq]),
                                                0xFFFFFF80u, cb + i2 * 16 + qq);
                            rk2[j] = med3(rk1[j], rk2[j], k);
                            rk1[j] = umn(rk1[j], k);
                        }
                    }
                    if ((t & 3) == 3) {  // chunk (128 cols) done: lg-reduce + write
                        unsigned c1 = rk1[j], c2 = rk2[j];
#pragma unroll
                        for (int off = 16; off < 64; off <<= 1) {
                            unsigned o1 = (unsigned)__shfl_xor((int)c1, off);
                            unsigned o2 = (unsigned)__shfl_xor((int)c2, off);
                            unsigned mx2 = umx(c1, o1);
                            c1 = umn(c1, o1);
                            c2 = umn(umn(c2, o2), mx2);
                        }
                        if (lg == 0) {
                            float m1f = __uint_as_float(c1 & 0xFFFFFF80u) - 0.5f;  // <= min
                            float m2f = __uint_as_float(c2 & 0xFFFFFF80u) - 0.5f;  // <= 2nd
                            wsp[(size_t)(wr0 + j * 16 + l15) * 64 + (q8 * 8 + (t >> 2))] =
                                make_uint2(__float_as_uint(m1f),
                                           (bf16_rd(m2f) << 16) | (c1 & 0x7Fu));
                        }
                        rk1[j] = 0xFFFFFFFFu; rk2[j] = 0xFFFFFFFFu;
                    }
                }
            }
        }
    }
}

// ---------- pass 2: candidate-column exact np re-eval + argmin + gather (proven) ----------
__global__ __launch_bounds__(256) void vq_pass2(
        const float* __restrict__ z, const float* __restrict__ e,
        const float* __restrict__ z2, const float* __restrict__ e2,
        const uint2* __restrict__ wsp, float* __restrict__ out) {
    __shared__ __align__(16) float zrow[4][ED];
    const int wid = threadIdx.x >> 6, lane = threadIdx.x & 63;
    const int r = blockIdx.x * 4 + wid;

    *reinterpret_cast<float4*>(&zrow[wid][lane * 4]) =
        *reinterpret_cast<const float4*>(z + (size_t)r * ED + lane * 4);
    __syncthreads();

    const float z2r = z2[r];
    uint2 p = wsp[(size_t)r * 64 + lane];                 // one 128-chunk per lane
    float m1 = __uint_as_float(p.x);
    int   i8 = (int)(p.y & 0xFFu);
    float m2 = __uint_as_float(p.y & 0xFFFF0000u);        // conservative (<= true m2)

    float rmn = m1;
#pragma unroll
    for (int off = 1; off < 64; off <<= 1) rmn = fminf(rmn, __shfl_xor(rmn, off));
    const float thr = rmn + DELTA;

    const bool cF = (m2 <= thr);
    const bool cS = (m1 <= thr) && !cF;
    unsigned long long bS = __ballot(cS);
    unsigned long long bF = __ballot(cF);

    float bd = 3.4e38f;
    int   bc = NE;

    // ---- single-column candidates: batch into lanes, one col per lane ----
    int myCol = -1;
    int cnt = 0;
    unsigned long long m = bS;
    while (true) {
        bool flush = (m == 0) || (cnt == 64);
        if (flush) {
            if (cnt > 0) {
                int ecol = (myCol >= 0) ? myCol : 0;
                const float* ec = e + (size_t)ecol * ED;
                float a0 = 0.f, a1 = 0.f, a2 = 0.f, a3 = 0.f;
#pragma unroll 8
                for (int t = 0; t < 64; ++t) {
                    float4 ev = *reinterpret_cast<const float4*>(ec + 4 * t);
                    float4 zv = *reinterpret_cast<const float4*>(&zrow[wid][4 * t]);
                    a0 = __fadd_rn(a0, __fmul_rn(zv.x, ev.x));
                    a1 = __fadd_rn(a1, __fmul_rn(zv.y, ev.y));
                    a2 = __fadd_rn(a2, __fmul_rn(zv.z, ev.z));
                    a3 = __fadd_rn(a3, __fmul_rn(zv.w, ev.w));
                }
                float s = __fadd_rn(__fadd_rn(a0, a1), __fadd_rn(a2, a3));
                float d = __fsub_rn(__fadd_rn(z2r, e2[ecol]), __fmul_rn(2.0f, s));
                if (myCol >= 0 && (d < bd || (d == bd && ecol < bc))) { bd = d; bc = ecol; }
                myCol = -1; cnt = 0;
            }
            if (m == 0) break;
        }
        int ch = __builtin_ctzll(m); m &= m - 1;
        int col = ch * 128 + __shfl(i8, ch);
        if (lane == cnt) myCol = col;
        ++cnt;
    }

    // ---- full-chunk candidates (rare; covers exact d'-ties automatically) ----
    m = bF;
    while (m) {
        int ch = __builtin_ctzll(m); m &= m - 1;
#pragma unroll
        for (int hh = 0; hh < 2; ++hh) {
            int col = ch * 128 + hh * 64 + lane;
            const float* ec = e + (size_t)col * ED;
            float a0 = 0.f, a1 = 0.f, a2 = 0.f, a3 = 0.f;
#pragma unroll 8
            for (int t = 0; t < 64; ++t) {
                float4 ev = *reinterpret_cast<const float4*>(ec + 4 * t);
                float4 zv = *reinterpret_cast<const float4*>(&zrow[wid][4 * t]);
                a0 = __fadd_rn(a0, __fmul_rn(zv.x, ev.x));
                a1 = __fadd_rn(a1, __fmul_rn(zv.y, ev.y));
                a2 = __fadd_rn(a2, __fmul_rn(zv.z, ev.z));
                a3 = __fadd_rn(a3, __fmul_rn(zv.w, ev.w));
            }
            float s = __fadd_rn(__fadd_rn(a0, a1), __fadd_rn(a2, a3));
            float d = __fsub_rn(__fadd_rn(z2r, e2[col]), __fmul_rn(2.0f, s));
            if (d < bd || (d == bd && col < bc)) { bd = d; bc = col; }
        }
    }

#pragma unroll
    for (int off = 1; off < 64; off <<= 1) {
        float od = __shfl_xor(bd, off);
        int   oc = __shfl_xor(bc, off);
        if (od < bd || (od == bd && oc < bc)) { bd = od; bc = oc; }
    }
    if (lane == 0) out[(size_t)BS * ED + r] = (float)bc;
    *reinterpret_cast<float4*>(out + (size_t)r * ED + lane * 4) =
        *reinterpret_cast<const float4*>(e + (size_t)bc * ED + lane * 4);
}

extern "C" void kernel_launch(void* const* d_in, const int* in_sizes, int n_in,
                              void* d_out, int out_size, void* d_ws, size_t ws_size,
                              hipStream_t stream) {
    const float* z = (const float*)d_in[0];
    const float* e = (const float*)d_in[1];
    float* out   = (float*)d_out;
    float* e2np  = (float*)d_ws;                     // 8192 f32 (exact, pass2 + slot)
    float* z2np  = e2np + NE;                        // 32768 f32
    uint2* wsp   = (uint2*)(z2np + BS);              // 32768 x 64 x 8B = 16 MB
    char*  ebT   = (char*)(wsp + (size_t)BS * 64);   // 9 planes x 512KB = 4.5 MB

    hipLaunchKernelGGL(sq_np_kernel, dim3(NE / 32), dim3(256), 0, stream, e, e2np);
    hipLaunchKernelGGL(sq_np_kernel, dim3(BS / 32), dim3(256), 0, stream, z, z2np);
    hipLaunchKernelGGL(cvt_ebT_kernel, dim3(NE * ED / 8 / 256), dim3(256), 0, stream,
                       e, e2np, ebT);
    hipLaunchKernelGGL(vq_pass1, dim3(1024), dim3(256), 0, stream, z, ebT, wsp);
    hipLaunchKernelGGL(vq_pass2, dim3(BS / 4), dim3(256), 0, stream, z, e, z2np, e2np, wsp, out);
}

// Round 19
// 258.970 us; speedup vs baseline: 1.0740x; 1.0740x over previous
//
#include <hip/hip_runtime.h>

constexpr int NE = 8192;
constexpr int ED = 256;
constexpr int BS = 32768;
constexpr float DELTA = 4e-4f;   // >> bf16-MFMA err + key quant (7.6e-6)

typedef short bf16x8 __attribute__((ext_vector_type(8)));
typedef float f32x4 __attribute__((ext_vector_type(4)));

constexpr size_t WSTR = (size_t)NE * 64;   // ebT k-window stride (512 KB)

#define GLOAD_LDS16(g, l) __builtin_amdgcn_global_load_lds( \
    (const __attribute__((address_space(1))) void*)(g),     \
    (__attribute__((address_space(3))) void*)(l), 16, 0, 0)

__device__ __forceinline__ short f2bf(float f) {            // RNE f32 -> bf16
    unsigned u = __float_as_uint(f);
    u = u + 0x7FFFu + ((u >> 16) & 1u);
    return (short)(u >> 16);
}
__device__ __forceinline__ unsigned bf16_rd(float x) {      // round toward -inf -> bf16 bits
    unsigned u = __float_as_uint(x);
    unsigned h = u >> 16;
    if ((u & 0x80000000u) && (u & 0xFFFFu)) ++h;
    return h;
}
__device__ __forceinline__ unsigned umn(unsigned a, unsigned b) { return a < b ? a : b; }
__device__ __forceinline__ unsigned umx(unsigned a, unsigned b) { return a > b ? a : b; }
__device__ __forceinline__ unsigned med3(unsigned a, unsigned b, unsigned c) {
    unsigned r;
    asm("v_med3_u32 %0, %1, %2, %3" : "=v"(r) : "v"(a), "v"(b), "v"(c));
    return r;
}
__device__ __forceinline__ unsigned and_or(unsigned a, unsigned b, unsigned c) {
    unsigned r;
    asm("v_and_or_b32 %0, %1, %2, %3" : "=v"(r) : "v"(a), "v"(b), "v"(c));
    return r;
}

// ---------- np-exact pairwise ||row||^2 for z AND e in one launch ----------
// rows [0,BS) -> z2 from z; rows [BS,BS+NE) -> e2 (exact) + e2p5 (=e2+0.5) from e.
__global__ void sq_np_kernel(const float* __restrict__ z, const float* __restrict__ e,
                             float* __restrict__ z2, float* __restrict__ e2,
                             float* __restrict__ e2p5) {
    int gtid = blockIdx.x * blockDim.x + threadIdx.x;
    int wave = gtid >> 6;
    int lane = threadIdx.x & 63;
    int sub  = lane & 7;
    int row  = wave * 8 + (lane >> 3);
    const float* p = (row < BS) ? (z + (size_t)row * ED)
                                : (e + (size_t)(row - BS) * ED);
    float b0 = 0.f, b1 = 0.f;
#pragma unroll
    for (int t = 0; t < 16; ++t) { float v = p[8 * t + sub];       b0 = __fadd_rn(b0, __fmul_rn(v, v)); }
#pragma unroll
    for (int t = 0; t < 16; ++t) { float v = p[128 + 8 * t + sub]; b1 = __fadd_rn(b1, __fmul_rn(v, v)); }
    b0 = __fadd_rn(b0, __shfl_xor(b0, 1));
    b0 = __fadd_rn(b0, __shfl_xor(b0, 2));
    b0 = __fadd_rn(b0, __shfl_xor(b0, 4));
    b1 = __fadd_rn(b1, __shfl_xor(b1, 1));
    b1 = __fadd_rn(b1, __shfl_xor(b1, 2));
    b1 = __fadd_rn(b1, __shfl_xor(b1, 4));
    float tot = __fadd_rn(b0, b1);
    if (sub == 0) {
        if (row < BS) {
            z2[row] = tot;
        } else {
            e2[row - BS]   = tot;
            e2p5[row - BS] = tot + 0.5f;
        }
    }
}

// ---------- e -> ebT (bf16 of -2e, k-major [w][col][64B]) ----------
__global__ void cvt_ebT_kernel(const float* __restrict__ e, char* __restrict__ ebT) {
    int i = blockIdx.x * blockDim.x + threadIdx.x;     // one per 16B unit (262144)
    int c = i >> 5;                                    // e-row (col in GEMM)
    int u = i & 31;
    int w = u >> 2, lg = u & 3;
    const float* p = e + (size_t)c * ED + w * 32 + lg * 8;
    float4 v0 = *reinterpret_cast<const float4*>(p);
    float4 v1 = *reinterpret_cast<const float4*>(p + 4);
    bf16x8 h;
    h[0] = f2bf(v0.x * -2.f); h[1] = f2bf(v0.y * -2.f);
    h[2] = f2bf(v0.z * -2.f); h[3] = f2bf(v0.w * -2.f);
    h[4] = f2bf(v1.x * -2.f); h[5] = f2bf(v1.y * -2.f);
    h[6] = f2bf(v1.z * -2.f); h[7] = f2bf(v1.w * -2.f);
    *reinterpret_cast<bf16x8*>(ebT + (size_t)w * WSTR + (size_t)c * 64 + lg * 16) = h;
}

// ---------- pass 1: R15 structure, e2 de-fused (LDS broadcast + VALU fadd) ----------
// 4 waves x 64 rows = 256 rows/block; col-quarter (2048) = 32 tiles of 64.
__global__ __launch_bounds__(256, 2) void vq_pass1(
        const float* __restrict__ z, const char* __restrict__ ebT,
        const float* __restrict__ e2p5, uint2* __restrict__ wsp) {
    __shared__ __align__(16) char Bs[2][32768];      // 64-col tile double buffer
    __shared__ float e2L[2048];                      // e2+0.5 for block's col range

    const int tid  = threadIdx.x;
    const int wid  = tid >> 6, lane = tid & 63;
    const int l15  = lane & 15, lg = lane >> 4;
    const int kblk = blockIdx.x;
    const int rg   = (kblk & 7) | ((kblk >> 5) << 3);   // all q of a rg on one XCD
    const int q    = (kblk >> 3) & 3;
    const int c0q  = q * 2048;
    const int wr0  = rg * 256 + wid * 64;

    // ---- staging source (pre-swizzled): LDS slot L holds logical (c=L>>5, r=(L&31)^(c&7))
    const char* gsrc[8];
#pragma unroll
    for (int it = 0; it < 8; ++it) {
        int L = it * 256 + tid;              // 0..2047
        int c = L >> 5;                      // col 0..63
        int r = (L & 31) ^ (c & 7);          // logical w*4+lg
        gsrc[it] = ebT + (size_t)(r >> 2) * WSTR + (size_t)(c0q + c) * 64 + (r & 3) * 16;
    }
#pragma unroll
    for (int it = 0; it < 8; ++it)           // stage tile 0
        GLOAD_LDS16(gsrc[it], &Bs[0][(it * 256 + tid) * 16]);

    // ---- e2+0.5 for this block's 2048 cols -> LDS (visible after first barrier) ----
    {
        float4 ea = *reinterpret_cast<const float4*>(e2p5 + c0q + tid * 8);
        float4 eb = *reinterpret_cast<const float4*>(e2p5 + c0q + tid * 8 + 4);
        *reinterpret_cast<float4*>(&e2L[tid * 8])     = ea;
        *reinterpret_cast<float4*>(&e2L[tid * 8 + 4]) = eb;
    }

    // ---- z rows -> registers (bf16), 64 rows/wave, full K (hides tile-0 latency) ----
    bf16x8 zreg[4][8];
#pragma unroll
    for (int j = 0; j < 4; ++j) {
        const float* zr = z + (size_t)(wr0 + j * 16 + l15) * ED + lg * 8;
#pragma unroll
        for (int t8 = 0; t8 < 8; ++t8) {
            float4 v0 = *reinterpret_cast<const float4*>(zr + t8 * 32);
            float4 v1 = *reinterpret_cast<const float4*>(zr + t8 * 32 + 4);
            bf16x8 h;
            h[0] = f2bf(v0.x); h[1] = f2bf(v0.y); h[2] = f2bf(v0.z); h[3] = f2bf(v0.w);
            h[4] = f2bf(v1.x); h[5] = f2bf(v1.y); h[6] = f2bf(v1.z); h[7] = f2bf(v1.w);
            zreg[j][t8] = h;
        }
    }

    // ---- ds_read address components: addr = col*512 + ((w*64+lg*16) ^ ((l15&7)<<4)) ----
    const int hsh = (l15 & 7) << 4;
    int xw[8];
#pragma unroll
    for (int w = 0; w < 8; ++w) xw[w] = (w * 64 + lg * 16) ^ hsh;

    unsigned rk1[4], rk2[4];

    for (int t = 0; t < 32; ++t) {
        __syncthreads();                 // vmcnt/lgkm drain: tile t + e2L staged
        if (t < 31) {                    // issue next tile into other buffer (hidden)
#pragma unroll
            for (int it = 0; it < 8; ++it)
                GLOAD_LDS16(gsrc[it] + (size_t)(t + 1) * 4096,
                            &Bs[(t + 1) & 1][(it * 256 + tid) * 16]);
        }
        const char* B = Bs[t & 1];
        f32x4 acc[2][4];
#pragma unroll
        for (int s = 0; s < 8; ++s) {
            const int i0 = (s >> 2) * 2;
            if ((s & 3) == 0) {
#pragma unroll
                for (int i2 = 0; i2 < 2; ++i2)
#pragma unroll
                    for (int j = 0; j < 4; ++j) acc[i2][j] = (f32x4){0.f, 0.f, 0.f, 0.f};
            }
            bf16x8 af[2][2];
#pragma unroll
            for (int i2 = 0; i2 < 2; ++i2)
#pragma unroll
                for (int tt = 0; tt < 2; ++tt)
                    af[i2][tt] = *reinterpret_cast<const bf16x8*>(
                        B + (size_t)((i0 + i2) * 16 + l15) * 512 + xw[(s & 3) * 2 + tt]);

            __builtin_amdgcn_s_setprio(1);
#pragma unroll
            for (int tt = 0; tt < 2; ++tt)
#pragma unroll
                for (int i2 = 0; i2 < 2; ++i2)
#pragma unroll
                    for (int j = 0; j < 4; ++j)
                        acc[i2][j] = __builtin_amdgcn_mfma_f32_16x16x32_bf16(
                            af[i2][tt], zreg[j][(s & 3) * 2 + tt],
                            acc[i2][j], 0, 0, 0);
            __builtin_amdgcn_s_setprio(0);

            if ((s & 3) == 3) {          // half-epilogue: cols i0*16 .. i0*16+31
                // e2+0.5 broadcast reads from LDS (same addr across l15: free)
                f32x4 e2v[2];
#pragma unroll
                for (int i2 = 0; i2 < 2; ++i2)
                    e2v[i2] = *reinterpret_cast<const f32x4*>(
                        &e2L[t * 64 + (i0 + i2) * 16 + lg * 4]);

                const unsigned cb = (unsigned)((t & 1) * 64 + lg * 4);
#pragma unroll
                for (int j = 0; j < 4; ++j) {
                    unsigned c1 = 0xFFFFFFFFu, c2 = 0xFFFFFFFFu;
#pragma unroll
                    for (int i2 = 0; i2 < 2; ++i2) {
#pragma unroll
                        for (int qq = 0; qq < 4; ++qq) {
                            // v = -2*dot + e2 + 0.5 = d' + 0.5 > 0: monotone u32 key
                            float v = __fadd_rn(acc[i2][j][qq], e2v[i2][qq]);
                            unsigned k = and_or(__float_as_uint(v), 0xFFFFFF80u,
                                                cb + (i0 + i2) * 16 + qq);
                            c2 = med3(c1, c2, k);
                            c1 = umn(c1, k);
                        }
                    }
                    if (i0 == 0) {       // first half of tile: stash
                        if ((t & 1) == 0) { rk1[j] = c1; rk2[j] = c2; }
                        else {
                            unsigned mxh = umx(rk1[j], c1);
                            rk1[j] = umn(rk1[j], c1);
                            rk2[j] = umn(umn(rk2[j], c2), mxh);
                        }
                    } else {             // second half: merge + lg-reduce (+ write on odd t)
                        unsigned mxh = umx(rk1[j], c1);
                        c1 = umn(rk1[j], c1);
                        c2 = umn(umn(rk2[j], c2), mxh);
                        if ((t & 1) == 0) {
                            rk1[j] = c1; rk2[j] = c2;
                        } else {
#pragma unroll
                            for (int off = 16; off < 64; off <<= 1) {
                                unsigned o1 = (unsigned)__shfl_xor((int)c1, off);
                                unsigned o2 = (unsigned)__shfl_xor((int)c2, off);
                                unsigned mx2 = umx(c1, o1);
                                c1 = umn(c1, o1);
                                c2 = umn(umn(c2, o2), mx2);
                            }
                            if (lg == 0) {
                                float m1f = __uint_as_float(c1 & 0xFFFFFF80u) - 0.5f;  // <= true min
                                float m2f = __uint_as_float(c2 & 0xFFFFFF80u) - 0.5f;  // <= true 2nd
                                wsp[(size_t)(wr0 + j * 16 + l15) * 64 + (q * 16 + (t >> 1))] =
                                    make_uint2(__float_as_uint(m1f),
                                               (bf16_rd(m2f) << 16) | (c1 & 0x7Fu));
                            }
                        }
                    }
                }
            }
        }
    }
}

// ---------- pass 2: candidate-column exact np re-eval + argmin + gather (proven) ----------
__global__ __launch_bounds__(256) void vq_pass2(
        const float* __restrict__ z, const float* __restrict__ e,
        const float* __restrict__ z2, const float* __restrict__ e2,
        const uint2* __restrict__ wsp, float* __restrict__ out) {
    __shared__ __align__(16) float zrow[4][ED];
    const int wid = threadIdx.x >> 6, lane = threadIdx.x & 63;
    const int r = blockIdx.x * 4 + wid;

    *reinterpret_cast<float4*>(&zrow[wid][lane * 4]) =
        *reinterpret_cast<const float4*>(z + (size_t)r * ED + lane * 4);
    __syncthreads();

    const float z2r = z2[r];
    uint2 p = wsp[(size_t)r * 64 + lane];                 // one 128-chunk per lane
    float m1 = __uint_as_float(p.x);
    int   i8 = (int)(p.y & 0xFFu);
    float m2 = __uint_as_float(p.y & 0xFFFF0000u);        // conservative (<= true m2)

    float rmn = m1;
#pragma unroll
    for (int off = 1; off < 64; off <<= 1) rmn = fminf(rmn, __shfl_xor(rmn, off));
    const float thr = rmn + DELTA;

    const bool cF = (m2 <= thr);
    const bool cS = (m1 <= thr) && !cF;
    unsigned long long bS = __ballot(cS);
    unsigned long long bF = __ballot(cF);

    float bd = 3.4e38f;
    int   bc = NE;

    // ---- single-column candidates: batch into lanes, one col per lane ----
    int myCol = -1;
    int cnt = 0;
    unsigned long long m = bS;
    while (true) {
        bool flush = (m == 0) || (cnt == 64);
        if (flush) {
            if (cnt > 0) {
                int ecol = (myCol >= 0) ? myCol : 0;
                const float* ec = e + (size_t)ecol * ED;
                float a0 = 0.f, a1 = 0.f, a2 = 0.f, a3 = 0.f;
#pragma unroll 8
                for (int t = 0; t < 64; ++t) {
                    float4 ev = *reinterpret_cast<const float4*>(ec + 4 * t);
                    float4 zv = *reinterpret_cast<const float4*>(&zrow[wid][4 * t]);
                    a0 = __fadd_rn(a0, __fmul_rn(zv.x, ev.x));
                    a1 = __fadd_rn(a1, __fmul_rn(zv.y, ev.y));
                    a2 = __fadd_rn(a2, __fmul_rn(zv.z, ev.z));
                    a3 = __fadd_rn(a3, __fmul_rn(zv.w, ev.w));
                }
                float s = __fadd_rn(__fadd_rn(a0, a1), __fadd_rn(a2, a3));
                float d = __fsub_rn(__fadd_rn(z2r, e2[ecol]), __fmul_rn(2.0f, s));
                if (myCol >= 0 && (d < bd || (d == bd && ecol < bc))) { bd = d; bc = ecol; }
                myCol = -1; cnt = 0;
            }
            if (m == 0) break;
        }
        int ch = __builtin_ctzll(m); m &= m - 1;
        int col = ch * 128 + __shfl(i8, ch);
        if (lane == cnt) myCol = col;
        ++cnt;
    }

    // ---- full-chunk candidates (rare; covers exact d'-ties automatically) ----
    m = bF;
    while (m) {
        int ch = __builtin_ctzll(m); m &= m - 1;
#pragma unroll
        for (int hh = 0; hh < 2; ++hh) {
            int col = ch * 128 + hh * 64 + lane;
            const float* ec = e + (size_t)col * ED;
            float a0 = 0.f, a1 = 0.f, a2 = 0.f, a3 = 0.f;
#pragma unroll 8
            for (int t = 0; t < 64; ++t) {
                float4 ev = *reinterpret_cast<const float4*>(ec + 4 * t);
                float4 zv = *reinterpret_cast<const float4*>(&zrow[wid][4 * t]);
                a0 = __fadd_rn(a0, __fmul_rn(zv.x, ev.x));
                a1 = __fadd_rn(a1, __fmul_rn(zv.y, ev.y));
                a2 = __fadd_rn(a2, __fmul_rn(zv.z, ev.z));
                a3 = __fadd_rn(a3, __fmul_rn(zv.w, ev.w));
            }
            float s = __fadd_rn(__fadd_rn(a0, a1), __fadd_rn(a2, a3));
            float d = __fsub_rn(__fadd_rn(z2r, e2[col]), __fmul_rn(2.0f, s));
            if (d < bd || (d == bd && col < bc)) { bd = d; bc = col; }
        }
    }

#pragma unroll
    for (int off = 1; off < 64; off <<= 1) {
        float od = __shfl_xor(bd, off);
        int   oc = __shfl_xor(bc, off);
        if (od < bd || (od == bd && oc < bc)) { bd = od; bc = oc; }
    }
    if (lane == 0) out[(size_t)BS * ED + r] = (float)bc;
    *reinterpret_cast<float4*>(out + (size_t)r * ED + lane * 4) =
        *reinterpret_cast<const float4*>(e + (size_t)bc * ED + lane * 4);
}

extern "C" void kernel_launch(void* const* d_in, const int* in_sizes, int n_in,
                              void* d_out, int out_size, void* d_ws, size_t ws_size,
                              hipStream_t stream) {
    const float* z = (const float*)d_in[0];
    const float* e = (const float*)d_in[1];
    float* out   = (float*)d_out;
    float* e2np  = (float*)d_ws;                     // 8192 f32 (exact)
    float* e2p5  = e2np + NE;                        // 8192 f32 (+0.5, pass1 keys)
    float* z2np  = e2p5 + NE;                        // 32768 f32
    uint2* wsp   = (uint2*)(z2np + BS);              // 32768 x 64 x 8B = 16 MB
    char*  ebT   = (char*)(wsp + (size_t)BS * 64);   // 8 planes x 512KB = 4 MB

    hipLaunchKernelGGL(sq_np_kernel, dim3((BS + NE) / 32), dim3(256), 0, stream,
                       z, e, z2np, e2np, e2p5);
    hipLaunchKernelGGL(cvt_ebT_kernel, dim3(NE * ED / 8 / 256), dim3(256), 0, stream,
                       e, ebT);
    hipLaunchKernelGGL(vq_pass1, dim3(512), dim3(256), 0, stream, z, ebT, e2p5, wsp);
    hipLaunchKernelGGL(vq_pass2, dim3(BS / 4), dim3(256), 0, stream, z, e, z2np, e2np, wsp, out);
}